// Round 7
// baseline (988.043 us; speedup 1.0000x reference)
//
#include <hip/hip_runtime.h>
#include <stdint.h>

// TransConv r7 = r5 kernel (best known: k_mega <= 41.6 us) + 4 timing probes.
// Probes decompose k_mega's stages via per-dispatch rocprof durations after
// three structural theories failed to move the ~44 us plateau. Probes write
// only to d_ws scratch; d_out path (k_prep + k_mega) is byte-identical to r5.

typedef unsigned short u16;
typedef unsigned int u32;
typedef __attribute__((ext_vector_type(8))) short bf16x8;
typedef __attribute__((ext_vector_type(8))) unsigned short u16x8;
typedef __attribute__((ext_vector_type(4))) float f32x4;

#define APAD 264   // As row stride (u16)

static __device__ __forceinline__ float bf2f(u16 u) {
  union { u32 i; float f; } c; c.i = ((u32)u) << 16; return c.f;
}
static __device__ __forceinline__ u16 f2bf(float f) {
  union { float ff; u32 i; } c; c.ff = f;
  u32 x = c.i;
  x += 0x7fffu + ((x >> 16) & 1u);   // RNE
  return (u16)(x >> 16);
}
static __device__ __forceinline__ bf16x8 as_bf(u16x8 v) {
  union { u16x8 a; bf16x8 b; } c; c.a = v; return c.b;
}

// ---------------------------------------------------------------------------
// Prep (unchanged from r5).
// ---------------------------------------------------------------------------
__global__ __launch_bounds__(256) void k_prep(
    const float* __restrict__ fc0_w,
    const float* __restrict__ wv0, const float* __restrict__ bv0,
    const float* __restrict__ wv1, const float* __restrict__ bv1,
    u16* __restrict__ w0T,
    u16* __restrict__ w2_0, float* __restrict__ bvm0,
    u16* __restrict__ w2_1, float* __restrict__ bvm1)
{
  const int bid = blockIdx.x, tid = threadIdx.x;
  if (bid < 32) {
    __shared__ u16 t[64][72];
    const int L  = bid >> 4;
    const int ti = (bid >> 2) & 3;
    const int tj = bid & 3;
    const float* wv = L ? wv1 : wv0;
    u16* W2 = L ? w2_1 : w2_0;
    const int cl = tid >> 2, dq = tid & 3;
    #pragma unroll
    for (int e = 0; e < 16; e++) {
      const int dl = dq * 16 + e;
      const float* p = wv + (size_t)(ti * 64 + cl) * 1024 + tj * 64 + dl;
      t[cl][dl] = f2bf(0.25f * (p[0] + p[256] + p[512] + p[768]));
    }
    __syncthreads();
    const int dl = tid >> 2, cq = tid & 3;
    u16x8 v0, v1;
    #pragma unroll
    for (int e = 0; e < 8; e++) { v0[e] = t[cq * 16 + e][dl]; v1[e] = t[cq * 16 + 8 + e][dl]; }
    const int kt = ti * 2 + (cq >> 1);
    const int q0 = (cq & 1) * 2;
    const int d  = tj * 64 + dl;
    u16* dst = W2 + kt * 8192 + d * 32 + q0 * 8;
    *(u16x8*)dst = v0;
    *(u16x8*)(dst + 8) = v1;
  } else {
    const int d = tid;
    u16x8 r0, r1;
    #pragma unroll
    for (int k = 0; k < 8; k++) {
      r0[k] = f2bf(fc0_w[k * 256 + d]);
      r1[k] = f2bf(fc0_w[(k + 8) * 256 + d]);
    }
    *(u16x8*)(w0T + d * 16) = r0;
    *(u16x8*)(w0T + d * 16 + 8) = r1;
    float t0 = 0.f, t1 = 0.f;
    #pragma unroll
    for (int h = 0; h < 4; h++) { t0 += bv0[h * 256 + d]; t1 += bv1[h * 256 + d]; }
    bvm0[d] = 0.25f * t0;
    bvm1[d] = 0.25f * t1;
  }
}

// ---------------------------------------------------------------------------
// Mega kernel (unchanged from r5): 1024 blocks x 256 thr, 32 rows/block.
// ---------------------------------------------------------------------------
__global__ __launch_bounds__(256, 4) void k_mega(
    const float* __restrict__ x,
    const u16* __restrict__ w0T, const float* __restrict__ fc0_b,
    const float* __restrict__ ln0w, const float* __restrict__ ln0b,
    const u16* __restrict__ w2_0, const float* __restrict__ bvm0,
    const float* __restrict__ ln1w, const float* __restrict__ ln1b,
    const u16* __restrict__ w2_1, const float* __restrict__ bvm1,
    const float* __restrict__ ln2w, const float* __restrict__ ln2b,
    float* __restrict__ out)
{
  __shared__ u16 As[32 * APAD];
  __shared__ float psum[4][32], pssq[4][32];
  __shared__ float stats[32][2];

  const int tid  = threadIdx.x;
  const int lane = tid & 63;
  const int wn   = tid >> 6;
  const int fr   = lane & 15;
  const int fq   = lane >> 4;
  const int kc   = fq << 3;
  const int m0   = blockIdx.x * 32;

  f32x4 acc[2][4];
  #pragma unroll
  for (int i = 0; i < 2; i++)
    #pragma unroll
    for (int j = 0; j < 4; j++)
      acc[i][j] = f32x4{0.f, 0.f, 0.f, 0.f};

  {
    bf16x8 af[2], bg[4];
    if (kc < 16) {
      #pragma unroll
      for (int i = 0; i < 2; i++) {
        const float* xp = x + (size_t)(m0 + i * 16 + fr) * 16 + kc;
        const f32x4 lo = *(const f32x4*)xp;
        const f32x4 hi = *(const f32x4*)(xp + 4);
        u16x8 v;
        #pragma unroll
        for (int e = 0; e < 4; e++) { v[e] = f2bf(lo[e]); v[4 + e] = f2bf(hi[e]); }
        af[i] = as_bf(v);
      }
      #pragma unroll
      for (int j = 0; j < 4; j++)
        bg[j] = as_bf(*(const u16x8*)(w0T + (wn * 64 + j * 16 + fr) * 16 + kc));
    } else {
      const u16x8 z = {0,0,0,0,0,0,0,0};
      #pragma unroll
      for (int i = 0; i < 2; i++) af[i] = as_bf(z);
      #pragma unroll
      for (int j = 0; j < 4; j++) bg[j] = as_bf(z);
    }
    #pragma unroll
    for (int i = 0; i < 2; i++)
      #pragma unroll
      for (int j = 0; j < 4; j++)
        acc[i][j] = __builtin_amdgcn_mfma_f32_16x16x32_bf16(af[i], bg[j], acc[i][j], 0, 0, 0);
  }

  {
    float vb[4], vw[4], vl[4];
    #pragma unroll
    for (int j = 0; j < 4; j++) {
      const int c = wn * 64 + j * 16 + fr;
      vb[j] = fc0_b[c]; vw[j] = ln0w[c]; vl[j] = ln0b[c];
    }
    #pragma unroll
    for (int i = 0; i < 2; i++)
      #pragma unroll
      for (int r = 0; r < 4; r++) {
        const int row = i * 16 + fq * 4 + r;
        float s = 0.f, ss = 0.f;
        #pragma unroll
        for (int j = 0; j < 4; j++) {
          const float xv = acc[i][j][r] + vb[j];
          acc[i][j][r] = xv;
          s += xv; ss += xv * xv;
        }
        #pragma unroll
        for (int off = 1; off < 16; off <<= 1) {
          s  += __shfl_xor(s, off, 64);
          ss += __shfl_xor(ss, off, 64);
        }
        if (fr == 0) { psum[wn][row] = s; pssq[wn][row] = ss; }
      }
    __syncthreads();
    if (tid < 32) {
      const float s  = psum[0][tid] + psum[1][tid] + psum[2][tid] + psum[3][tid];
      const float ss = pssq[0][tid] + pssq[1][tid] + pssq[2][tid] + pssq[3][tid];
      const float mean = s * (1.0f / 256.0f);
      const float var  = ss * (1.0f / 256.0f) - mean * mean;
      stats[tid][0] = mean;
      stats[tid][1] = rsqrtf(var + 1e-5f);
    }
    __syncthreads();
    #pragma unroll
    for (int i = 0; i < 2; i++)
      #pragma unroll
      for (int r = 0; r < 4; r++) {
        const int row = i * 16 + fq * 4 + r;
        const float mean = stats[row][0], rstd = stats[row][1];
        #pragma unroll
        for (int j = 0; j < 4; j++) {
          const int col = wn * 64 + j * 16 + fr;
          const float y = fmaxf((acc[i][j][r] - mean) * rstd * vw[j] + vl[j], 0.f);
          const u32 self = f2bf(y);
          const u32 peer = __shfl_xor((int)self, 1, 64);
          if ((fr & 1) == 0)
            *(u32*)&As[row * APAD + col] = self | (peer << 16);
        }
      }
    __syncthreads();
  }

  #pragma unroll 1
  for (int p = 0; p < 2; p++) {
    const u16* W2 = p ? w2_1 : w2_0;
    const float* bvp = p ? bvm1 : bvm0;
    const float* lw  = p ? ln2w : ln1w;
    const float* lb  = p ? ln2b : ln1b;

    #pragma unroll
    for (int i = 0; i < 2; i++)
      #pragma unroll
      for (int j = 0; j < 4; j++)
        acc[i][j] = f32x4{0.f, 0.f, 0.f, 0.f};

    const u16* wb = W2 + wn * 2048 + fr * 32 + kc;
    u16x8 bR[4];
    #pragma unroll
    for (int j = 0; j < 4; j++)
      bR[j] = *(const u16x8*)(wb + j * 512);
    #pragma unroll 1
    for (int kt = 0; kt < 8; kt++) {
      bf16x8 a[2], b[4];
      #pragma unroll
      for (int i = 0; i < 2; i++)
        a[i] = *(const bf16x8*)(As + (i * 16 + fr) * APAD + kt * 32 + kc);
      #pragma unroll
      for (int j = 0; j < 4; j++) b[j] = as_bf(bR[j]);
      if (kt < 7) {
        #pragma unroll
        for (int j = 0; j < 4; j++)
          bR[j] = *(const u16x8*)(wb + (kt + 1) * 8192 + j * 512);
      }
      #pragma unroll
      for (int i = 0; i < 2; i++)
        #pragma unroll
        for (int j = 0; j < 4; j++)
          acc[i][j] = __builtin_amdgcn_mfma_f32_16x16x32_bf16(a[i], b[j], acc[i][j], 0, 0, 0);
    }

    float vb[4], vw[4], vl[4];
    #pragma unroll
    for (int j = 0; j < 4; j++) {
      const int c = wn * 64 + j * 16 + fr;
      vb[j] = bvp[c]; vw[j] = lw[c]; vl[j] = lb[c];
    }
    #pragma unroll
    for (int i = 0; i < 2; i++)
      #pragma unroll
      for (int r = 0; r < 4; r++) {
        const int row = i * 16 + fq * 4 + r;
        float s = 0.f, ss = 0.f;
        #pragma unroll
        for (int j = 0; j < 4; j++) {
          const int col = wn * 64 + j * 16 + fr;
          const float prev = bf2f(As[row * APAD + col]);
          const float xv = (acc[i][j][r] + vb[j] + prev) * 0.5f;
          acc[i][j][r] = xv;
          s += xv; ss += xv * xv;
        }
        #pragma unroll
        for (int off = 1; off < 16; off <<= 1) {
          s  += __shfl_xor(s, off, 64);
          ss += __shfl_xor(ss, off, 64);
        }
        if (fr == 0) { psum[wn][row] = s; pssq[wn][row] = ss; }
      }
    __syncthreads();
    if (tid < 32) {
      const float s  = psum[0][tid] + psum[1][tid] + psum[2][tid] + psum[3][tid];
      const float ss = pssq[0][tid] + pssq[1][tid] + pssq[2][tid] + pssq[3][tid];
      const float mean = s * (1.0f / 256.0f);
      const float var  = ss * (1.0f / 256.0f) - mean * mean;
      stats[tid][0] = mean;
      stats[tid][1] = rsqrtf(var + 1e-5f);
    }
    __syncthreads();
    if (p == 0) {
      #pragma unroll
      for (int i = 0; i < 2; i++)
        #pragma unroll
        for (int r = 0; r < 4; r++) {
          const int row = i * 16 + fq * 4 + r;
          const float mean = stats[row][0], rstd = stats[row][1];
          #pragma unroll
          for (int j = 0; j < 4; j++) {
            const int col = wn * 64 + j * 16 + fr;
            const float y = fmaxf((acc[i][j][r] - mean) * rstd * vw[j] + vl[j], 0.f);
            const u32 self = f2bf(y);
            const u32 peer = __shfl_xor((int)self, 1, 64);
            if ((fr & 1) == 0)
              *(u32*)&As[row * APAD + col] = self | (peer << 16);
          }
        }
      __syncthreads();
    } else {
      #pragma unroll
      for (int i = 0; i < 2; i++)
        #pragma unroll
        for (int r = 0; r < 4; r++) {
          const int row = i * 16 + fq * 4 + r;
          const float mean = stats[row][0], rstd = stats[row][1];
          #pragma unroll
          for (int j = 0; j < 4; j++) {
            const int col = wn * 64 + j * 16 + fr;
            const float y = fmaxf((acc[i][j][r] - mean) * rstd * vw[j] + vl[j], 0.f);
            out[(size_t)(m0 + row) * 256 + col] = y;
          }
        }
    }
  }
}

// ===========================================================================
// PROBES (write to d_ws scratch only; dropped next round)
// ===========================================================================

// P1: pure MFMA clock-o-meter. 96 reps x 64 register-only MFMA, no memory.
// Model @2.4GHz: ~50 us. >=120 us => effective compute clock <= 1.0 GHz.
__global__ __launch_bounds__(256, 4) void kp_mfma(float* __restrict__ sink)
{
  const int tid = threadIdx.x;
  f32x4 acc[2][4];
  #pragma unroll
  for (int i = 0; i < 2; i++)
    #pragma unroll
    for (int j = 0; j < 4; j++)
      acc[i][j] = f32x4{0.f, 0.f, 0.f, 0.f};
  u16x8 av, bv;
  #pragma unroll
  for (int e = 0; e < 8; e++) {
    av[e] = (u16)(0x3F80u ^ ((tid + e) & 31));
    bv[e] = (u16)(0x3F80u ^ ((tid * 3 + e) & 63));
  }
  const bf16x8 a = as_bf(av), b = as_bf(bv);
  #pragma unroll 1
  for (int rep = 0; rep < 96; rep++) {
    #pragma unroll
    for (int kt = 0; kt < 8; kt++)
      #pragma unroll
      for (int i = 0; i < 2; i++)
        #pragma unroll
        for (int j = 0; j < 4; j++)
          acc[i][j] = __builtin_amdgcn_mfma_f32_16x16x32_bf16(a, b, acc[i][j], 0, 0, 0);
  }
  float s = 0.f;
  #pragma unroll
  for (int i = 0; i < 2; i++)
    #pragma unroll
    for (int j = 0; j < 4; j++)
      #pragma unroll
      for (int r = 0; r < 4; r++) s += acc[i][j][r];
  sink[blockIdx.x * 256 + tid] = s;
}

// P2: exact K-loop phase x 32 (16 reps x 2 layers). LICM defeated via opaque
// zero offset per rep. Per-phase cost = T/32.
__global__ __launch_bounds__(256, 4) void kp_kloop(
    const u16* __restrict__ w2_0, const u16* __restrict__ w2_1, float* __restrict__ sink)
{
  __shared__ u16 As[32 * APAD];
  const int tid = threadIdx.x;
  const int lane = tid & 63;
  const int wn = tid >> 6;
  const int fr = lane & 15;
  const int fq = lane >> 4;
  const int kc = fq << 3;
  for (int i = tid; i < 16 * APAD; i += 256) ((u32*)As)[i] = 0x3F803F80u;
  __syncthreads();

  f32x4 acc[2][4];
  #pragma unroll
  for (int i = 0; i < 2; i++)
    #pragma unroll
    for (int j = 0; j < 4; j++)
      acc[i][j] = f32x4{0.f, 0.f, 0.f, 0.f};

  u32 zoff = 0;                      // stays 0; opaque to the compiler
  #pragma unroll 1
  for (int rep = 0; rep < 16; rep++) {
    asm volatile("" : "+v"(zoff));
    #pragma unroll 1
    for (int p = 0; p < 2; p++) {
      const u16* W2 = p ? w2_1 : w2_0;
      const u16* wb = W2 + zoff + wn * 2048 + fr * 32 + kc;
      u16x8 bR[4];
      #pragma unroll
      for (int j = 0; j < 4; j++) bR[j] = *(const u16x8*)(wb + j * 512);
      #pragma unroll 1
      for (int kt = 0; kt < 8; kt++) {
        bf16x8 a[2], b[4];
        #pragma unroll
        for (int i = 0; i < 2; i++)
          a[i] = *(const bf16x8*)(As + zoff + (i * 16 + fr) * APAD + kt * 32 + kc);
        #pragma unroll
        for (int j = 0; j < 4; j++) b[j] = as_bf(bR[j]);
        if (kt < 7) {
          #pragma unroll
          for (int j = 0; j < 4; j++)
            bR[j] = *(const u16x8*)(wb + (kt + 1) * 8192 + j * 512);
        }
        #pragma unroll
        for (int i = 0; i < 2; i++)
          #pragma unroll
          for (int j = 0; j < 4; j++)
            acc[i][j] = __builtin_amdgcn_mfma_f32_16x16x32_bf16(a[i], b[j], acc[i][j], 0, 0, 0);
      }
    }
  }
  float s = 0.f;
  #pragma unroll
  for (int i = 0; i < 2; i++)
    #pragma unroll
    for (int j = 0; j < 4; j++)
      #pragma unroll
      for (int r = 0; r < 4; r++) s += acc[i][j][r];
  sink[blockIdx.x * 256 + tid] = s;
}

// P3: exact epilogue x 16 (shfl reduce + stats + As write-back, 3 barriers).
// State evolves across reps (As chain) -> no LICM issue. Per-epi cost = T/16.
__global__ __launch_bounds__(256, 4) void kp_epi(
    const float* __restrict__ bvp, const float* __restrict__ lwp,
    const float* __restrict__ lbp, float* __restrict__ sink)
{
  __shared__ u16 As[32 * APAD];
  __shared__ float psum[4][32], pssq[4][32];
  __shared__ float stats[32][2];
  const int tid = threadIdx.x;
  const int lane = tid & 63;
  const int wn = tid >> 6;
  const int fr = lane & 15;
  const int fq = lane >> 4;
  for (int i = tid; i < 16 * APAD; i += 256) ((u32*)As)[i] = 0x3F803F80u;

  f32x4 acc[2][4];
  #pragma unroll
  for (int i = 0; i < 2; i++)
    #pragma unroll
    for (int j = 0; j < 4; j++)
      #pragma unroll
      for (int r = 0; r < 4; r++)
        acc[i][j][r] = (float)((tid + i * 3 + j * 5 + r * 7) & 15) * 0.125f;
  __syncthreads();

  float vb[4], vw[4], vl[4];
  #pragma unroll
  for (int j = 0; j < 4; j++) {
    const int c = wn * 64 + j * 16 + fr;
    vb[j] = bvp[c]; vw[j] = lwp[c]; vl[j] = lbp[c];
  }

  #pragma unroll 1
  for (int rep = 0; rep < 16; rep++) {
    #pragma unroll
    for (int i = 0; i < 2; i++)
      #pragma unroll
      for (int r = 0; r < 4; r++) {
        const int row = i * 16 + fq * 4 + r;
        float s = 0.f, ss = 0.f;
        #pragma unroll
        for (int j = 0; j < 4; j++) {
          const int col = wn * 64 + j * 16 + fr;
          const float prev = bf2f(As[row * APAD + col]);
          const float xv = (acc[i][j][r] + vb[j] + prev) * 0.5f;
          acc[i][j][r] = xv;
          s += xv; ss += xv * xv;
        }
        #pragma unroll
        for (int off = 1; off < 16; off <<= 1) {
          s  += __shfl_xor(s, off, 64);
          ss += __shfl_xor(ss, off, 64);
        }
        if (fr == 0) { psum[wn][row] = s; pssq[wn][row] = ss; }
      }
    __syncthreads();
    if (tid < 32) {
      const float s  = psum[0][tid] + psum[1][tid] + psum[2][tid] + psum[3][tid];
      const float ss = pssq[0][tid] + pssq[1][tid] + pssq[2][tid] + pssq[3][tid];
      const float mean = s * (1.0f / 256.0f);
      const float var  = ss * (1.0f / 256.0f) - mean * mean;
      stats[tid][0] = mean;
      stats[tid][1] = rsqrtf(var + 1e-5f);
    }
    __syncthreads();
    #pragma unroll
    for (int i = 0; i < 2; i++)
      #pragma unroll
      for (int r = 0; r < 4; r++) {
        const int row = i * 16 + fq * 4 + r;
        const float mean = stats[row][0], rstd = stats[row][1];
        #pragma unroll
        for (int j = 0; j < 4; j++) {
          const int col = wn * 64 + j * 16 + fr;
          const float y = fmaxf((acc[i][j][r] - mean) * rstd * vw[j] + vl[j], 0.f);
          const u32 self = f2bf(y);
          const u32 peer = __shfl_xor((int)self, 1, 64);
          if ((fr & 1) == 0)
            *(u32*)&As[row * APAD + col] = self | (peer << 16);
        }
      }
    __syncthreads();
  }
  sink[blockIdx.x * 256 + tid] =
      stats[tid & 31][0] + acc[0][0][0] + bf2f(As[(tid & 31) * APAD + (tid >> 3)]);
}

// P4: weight loads only, 32 reps x 32 loads (LICM-defeated). Load-path floor.
__global__ __launch_bounds__(256, 4) void kp_wload(
    const u16* __restrict__ w2_0, float* __restrict__ sink)
{
  const int tid = threadIdx.x;
  const int lane = tid & 63;
  const int wn = tid >> 6;
  const int fr = lane & 15;
  const int kc = (lane >> 4) << 3;
  u32 s = 1u;
  u32 zoff = 0;
  const u16* wb = w2_0 + wn * 2048 + fr * 32 + kc;
  #pragma unroll 1
  for (int rep = 0; rep < 32; rep++) {
    asm volatile("" : "+v"(zoff));
    #pragma unroll 1
    for (int kt = 0; kt < 8; kt++) {
      #pragma unroll
      for (int j = 0; j < 4; j++) {
        const u16x8 v = *(const u16x8*)(wb + zoff + kt * 8192 + j * 512);
        s ^= ((u32)v[0]) | (((u32)v[7]) << 16);
      }
    }
  }
  sink[blockIdx.x * 256 + tid] = (float)(s & 0xFFFFu);
}

// ---------------------------------------------------------------------------
extern "C" void kernel_launch(void* const* d_in, const int* in_sizes, int n_in,
                              void* d_out, int out_size, void* d_ws, size_t ws_size,
                              hipStream_t stream)
{
  (void)in_sizes; (void)n_in; (void)out_size; (void)ws_size;
  const float* x     = (const float*)d_in[0];
  const float* fc0_w = (const float*)d_in[2];
  const float* fc0_b = (const float*)d_in[3];
  const float* ln0_w = (const float*)d_in[4];
  const float* ln0_b = (const float*)d_in[5];
  const float* ln1_w = (const float*)d_in[6];
  const float* ln1_b = (const float*)d_in[7];
  const float* ln2_w = (const float*)d_in[8];
  const float* ln2_b = (const float*)d_in[9];
  const float* wv0_w = (const float*)d_in[14];
  const float* wv0_b = (const float*)d_in[15];
  const float* wv1_w = (const float*)d_in[20];
  const float* wv1_b = (const float*)d_in[21];

  char* ws = (char*)d_ws;
  u16*   w2_0 = (u16*)(ws);                  // 128 KB (K-major)
  u16*   w2_1 = (u16*)(ws + 131072ull);      // 128 KB
  u16*   w0T  = (u16*)(ws + 262144ull);      // 8 KB
  float* bvm0 = (float*)(ws + 270336ull);
  float* bvm1 = (float*)(ws + 271360ull);
  float* snk1 = (float*)(ws + 4194304ull);   // probe sinks, 1 MB each
  float* snk2 = (float*)(ws + 6291456ull);
  float* snk3 = (float*)(ws + 8388608ull);
  float* snk4 = (float*)(ws + 10485760ull);

  k_prep<<<33, 256, 0, stream>>>(fc0_w, wv0_w, wv0_b, wv1_w, wv1_b,
                                 w0T, w2_0, bvm0, w2_1, bvm1);
  k_mega<<<1024, 256, 0, stream>>>(x, w0T, fc0_b, ln0_w, ln0_b,
                                   w2_0, bvm0, ln1_w, ln1_b,
                                   w2_1, bvm1, ln2_w, ln2_b,
                                   (float*)d_out);
  // --- diagnostic probes (scratch-only) ---
  kp_mfma <<<1024, 256, 0, stream>>>(snk1);
  kp_kloop<<<1024, 256, 0, stream>>>(w2_0, w2_1, snk2);
  kp_epi  <<<1024, 256, 0, stream>>>(bvm0, ln1_w, ln1_b, snk3);
  kp_wload<<<1024, 256, 0, stream>>>(w2_0, snk4);
}

// Round 8
// 95.886 us; speedup vs baseline: 10.3043x; 10.3043x over previous
//
#include <hip/hip_runtime.h>
#include <stdint.h>

// TransConv fused form, round 8. Fixed geometry: B=16, L=2048, N=32768,
// Cin=16, D=256, H=4. Validated algebra (r2-r7, absmax 0.0625):
//   h <- relu(LN((h @ Wv_mean + bvm + h)/2)),  Wv_mean = head-mean of Wv,
// fc0: h0 = relu(LN(x @ fc0_w + fc0_b)).
//
// r7 probe finding: weight-load path = the bottleneck; L2 serves ~8 lines/cyc/XCD
// -> minimize line-REQUESTS (= waves x lines-per-wave), not traffic.
// r8 structure: 256 blocks x 16 waves (1024 thr), block owns 128 rows.
// Wave w owns a UNIQUE 16-col stripe (col = w*16 + lane&15) x all 128 rows:
// weights per wave = 8KB disjoint -> block pulls 256KB redundancy-free,
// direct to registers, K-loop barrier-free. h tile in 66.5KB LDS;
// row-stats cross-wave via LDS atomicAdd (ds_add_f32).

typedef unsigned short u16;
typedef unsigned int u32;
typedef __attribute__((ext_vector_type(8))) short bf16x8;
typedef __attribute__((ext_vector_type(8))) unsigned short u16x8;
typedef __attribute__((ext_vector_type(4))) float f32x4;

#define APAD 260   // As row stride (u16); 520B rows -> 2-way LDS aliasing (free)

static __device__ __forceinline__ float bf2f(u16 u) {
  union { u32 i; float f; } c; c.i = ((u32)u) << 16; return c.f;
}
static __device__ __forceinline__ u16 f2bf(float f) {
  union { float ff; u32 i; } c; c.ff = f;
  u32 x = c.i;
  x += 0x7fffu + ((x >> 16) & 1u);   // RNE
  return (u16)(x >> 16);
}
static __device__ __forceinline__ bf16x8 as_bf(u16x8 v) {
  union { u16x8 a; bf16x8 b; } c; c.a = v; return c.b;
}

// ---------------------------------------------------------------------------
// Prep (unchanged from r5). grid 33 x 256.
//  bid 0..31 : W2{L}[kt][d][q][e] = bf16(mean_h wv{L}[kt*32+q*8+e][h*256+d])
//  bid 32    : w0T[d][k] = bf16(fc0_w[k][d]);  bvm{L}[d] = mean_h bv{L}
// ---------------------------------------------------------------------------
__global__ __launch_bounds__(256) void k_prep(
    const float* __restrict__ fc0_w,
    const float* __restrict__ wv0, const float* __restrict__ bv0,
    const float* __restrict__ wv1, const float* __restrict__ bv1,
    u16* __restrict__ w0T,
    u16* __restrict__ w2_0, float* __restrict__ bvm0,
    u16* __restrict__ w2_1, float* __restrict__ bvm1)
{
  const int bid = blockIdx.x, tid = threadIdx.x;
  if (bid < 32) {
    __shared__ u16 t[64][72];
    const int L  = bid >> 4;
    const int ti = (bid >> 2) & 3;
    const int tj = bid & 3;
    const float* wv = L ? wv1 : wv0;
    u16* W2 = L ? w2_1 : w2_0;
    const int cl = tid >> 2, dq = tid & 3;
    #pragma unroll
    for (int e = 0; e < 16; e++) {
      const int dl = dq * 16 + e;
      const float* p = wv + (size_t)(ti * 64 + cl) * 1024 + tj * 64 + dl;
      t[cl][dl] = f2bf(0.25f * (p[0] + p[256] + p[512] + p[768]));
    }
    __syncthreads();
    const int dl = tid >> 2, cq = tid & 3;
    u16x8 v0, v1;
    #pragma unroll
    for (int e = 0; e < 8; e++) { v0[e] = t[cq * 16 + e][dl]; v1[e] = t[cq * 16 + 8 + e][dl]; }
    const int kt = ti * 2 + (cq >> 1);
    const int q0 = (cq & 1) * 2;
    const int d  = tj * 64 + dl;
    u16* dst = W2 + kt * 8192 + d * 32 + q0 * 8;
    *(u16x8*)dst = v0;
    *(u16x8*)(dst + 8) = v1;
  } else {
    const int d = tid;
    u16x8 r0, r1;
    #pragma unroll
    for (int k = 0; k < 8; k++) {
      r0[k] = f2bf(fc0_w[k * 256 + d]);
      r1[k] = f2bf(fc0_w[(k + 8) * 256 + d]);
    }
    *(u16x8*)(w0T + d * 16) = r0;
    *(u16x8*)(w0T + d * 16 + 8) = r1;
    float t0 = 0.f, t1 = 0.f;
    #pragma unroll
    for (int h = 0; h < 4; h++) { t0 += bv0[h * 256 + d]; t1 += bv1[h * 256 + d]; }
    bvm0[d] = 0.25f * t0;
    bvm1[d] = 0.25f * t1;
  }
}

// ---------------------------------------------------------------------------
// Mega kernel: 256 blocks x 1024 threads (16 waves), block owns 128 rows.
// Wave w owns cols [w*16, w*16+16); each lane owns col = w*16 + (lane&15).
// acc[8]: i-th frag covers rows i*16 + fq*4 + r (C/D map m89/m91, j-dim = 1).
// ---------------------------------------------------------------------------
__global__ __launch_bounds__(1024, 1) void k_mega(
    const float* __restrict__ x,
    const u16* __restrict__ w0T, const float* __restrict__ fc0_b,
    const float* __restrict__ ln0w, const float* __restrict__ ln0b,
    const u16* __restrict__ w2_0, const float* __restrict__ bvm0,
    const float* __restrict__ ln1w, const float* __restrict__ ln1b,
    const u16* __restrict__ w2_1, const float* __restrict__ bvm1,
    const float* __restrict__ ln2w, const float* __restrict__ ln2b,
    float* __restrict__ out)
{
  __shared__ u16 As[128 * APAD];        // 66560 B: the h tile
  __shared__ float psum[128], pssq[128];
  __shared__ float stats[128][2];

  const int tid  = threadIdx.x;
  const int lane = tid & 63;
  const int w    = tid >> 6;        // 0..15: col-stripe
  const int fr   = lane & 15;
  const int fq   = lane >> 4;
  const int kc   = fq << 3;         // k sub-chunk (0,8,16,24)
  const int m0   = blockIdx.x * 128;
  const int col  = w * 16 + fr;     // this lane's single output column

  if (tid < 128) { psum[tid] = 0.f; pssq[tid] = 0.f; }

  f32x4 acc[8];
  #pragma unroll
  for (int i = 0; i < 8; i++) acc[i] = f32x4{0.f, 0.f, 0.f, 0.f};

  // ---- Phase 0 MFMA: fc0 (K=16 zero-padded to 32), operands from global ----
  {
    u16x8 bv = {0, 0, 0, 0, 0, 0, 0, 0};
    if (kc < 16) bv = *(const u16x8*)(w0T + col * 16 + kc);
    const bf16x8 bg = as_bf(bv);
    #pragma unroll
    for (int i = 0; i < 8; i++) {
      u16x8 av = {0, 0, 0, 0, 0, 0, 0, 0};
      if (kc < 16) {
        const float* xp = x + (size_t)(m0 + i * 16 + fr) * 16 + kc;
        const f32x4 lo = *(const f32x4*)xp;
        const f32x4 hi = *(const f32x4*)(xp + 4);
        #pragma unroll
        for (int e = 0; e < 4; e++) { av[e] = f2bf(lo[e]); av[4 + e] = f2bf(hi[e]); }
      }
      acc[i] = __builtin_amdgcn_mfma_f32_16x16x32_bf16(as_bf(av), bg, acc[i], 0, 0, 0);
    }
  }

  __syncthreads();   // A0: psum zeroing done before any atomics

  // ---- Phase 0 epilogue: +fc0_b, row-LN(ln0), relu -> As ----
  {
    const float vb = fc0_b[col];
    #pragma unroll
    for (int i = 0; i < 8; i++)
      #pragma unroll
      for (int r = 0; r < 4; r++) {
        const int row = i * 16 + fq * 4 + r;
        const float xv = acc[i][r] + vb;
        acc[i][r] = xv;
        float s = xv, ss = xv * xv;
        #pragma unroll
        for (int off = 1; off < 16; off <<= 1) {
          s  += __shfl_xor(s, off, 64);
          ss += __shfl_xor(ss, off, 64);
        }
        if (fr == 0) { atomicAdd(&psum[row], s); atomicAdd(&pssq[row], ss); }
      }
    __syncthreads();   // B0: atomics done
    if (tid < 128) {
      const float s = psum[tid], ss = pssq[tid];
      const float mean = s * (1.0f / 256.0f);
      const float var  = ss * (1.0f / 256.0f) - mean * mean;
      stats[tid][0] = mean;
      stats[tid][1] = rsqrtf(var + 1e-5f);
      psum[tid] = 0.f; pssq[tid] = 0.f;   // re-zero for next phase
    }
    __syncthreads();   // C0: stats ready
    const float vw = ln0w[col], vl = ln0b[col];
    #pragma unroll
    for (int i = 0; i < 8; i++)
      #pragma unroll
      for (int r = 0; r < 4; r++) {
        const int row = i * 16 + fq * 4 + r;
        const float y = fmaxf((acc[i][r] - stats[row][0]) * stats[row][1] * vw + vl, 0.f);
        const u32 self = f2bf(y);
        const u32 peer = __shfl_xor((int)self, 1, 64);   // pack bf16 pair
        if ((fr & 1) == 0)
          *(u32*)&As[row * APAD + col] = self | (peer << 16);
      }
    __syncthreads();   // D0: h0 visible to all waves
  }

  // ---- Phases 1 & 2: h <- relu(LN((h @ W + bvm + h)/2)) ----
  #pragma unroll 1
  for (int p = 0; p < 2; p++) {
    const u16* W2 = p ? w2_1 : w2_0;
    const float* bvp = p ? bvm1 : bvm0;
    const float* lw  = p ? ln2w : ln1w;
    const float* lb  = p ? ln2b : ln1b;

    #pragma unroll
    for (int i = 0; i < 8; i++) acc[i] = f32x4{0.f, 0.f, 0.f, 0.f};

    // barrier-free K-loop: A (h) from LDS, B (weights) per-wave-unique from
    // global. Per wave-load: lanes cover [w*1KB, w*1KB+1KB) contiguous.
    const u16* wb = W2 + col * 32 + kc;
    u16x8 bp0 = *(const u16x8*)(wb);
    u16x8 bp1 = *(const u16x8*)(wb + 8192);
    #pragma unroll
    for (int kt = 0; kt < 8; kt++) {
      bf16x8 a[8];
      #pragma unroll
      for (int i = 0; i < 8; i++)
        a[i] = *(const bf16x8*)(As + (i * 16 + fr) * APAD + kt * 32 + kc);
      const bf16x8 bcur = as_bf((kt & 1) ? bp1 : bp0);
      if (kt < 6) {                        // depth-2 prefetch
        const u16x8 nv = *(const u16x8*)(wb + (kt + 2) * 8192);
        if (kt & 1) bp1 = nv; else bp0 = nv;
      }
      #pragma unroll
      for (int i = 0; i < 8; i++)
        acc[i] = __builtin_amdgcn_mfma_f32_16x16x32_bf16(a[i], bcur, acc[i], 0, 0, 0);
    }

    // epilogue: xv = (C + bvm + h_prev)/2, row-LN, relu
    const float vb = bvp[col];
    #pragma unroll
    for (int i = 0; i < 8; i++)
      #pragma unroll
      for (int r = 0; r < 4; r++) {
        const int row = i * 16 + fq * 4 + r;
        const float prev = bf2f(As[row * APAD + col]);
        const float xv = (acc[i][r] + vb + prev) * 0.5f;
        acc[i][r] = xv;
        float s = xv, ss = xv * xv;
        #pragma unroll
        for (int off = 1; off < 16; off <<= 1) {
          s  += __shfl_xor(s, off, 64);
          ss += __shfl_xor(ss, off, 64);
        }
        if (fr == 0) { atomicAdd(&psum[row], s); atomicAdd(&pssq[row], ss); }
      }
    __syncthreads();   // B: atomics done (and all prev-reads done)
    if (tid < 128) {
      const float s = psum[tid], ss = pssq[tid];
      const float mean = s * (1.0f / 256.0f);
      const float var  = ss * (1.0f / 256.0f) - mean * mean;
      stats[tid][0] = mean;
      stats[tid][1] = rsqrtf(var + 1e-5f);
      psum[tid] = 0.f; pssq[tid] = 0.f;
    }
    __syncthreads();   // C: stats ready
    const float vw = lw[col], vl = lb[col];
    if (p == 0) {
      #pragma unroll
      for (int i = 0; i < 8; i++)
        #pragma unroll
        for (int r = 0; r < 4; r++) {
          const int row = i * 16 + fq * 4 + r;
          const float y = fmaxf((acc[i][r] - stats[row][0]) * stats[row][1] * vw + vl, 0.f);
          const u32 self = f2bf(y);
          const u32 peer = __shfl_xor((int)self, 1, 64);
          if ((fr & 1) == 0)
            *(u32*)&As[row * APAD + col] = self | (peer << 16);
        }
      __syncthreads();   // D: new h visible before next K-loop
    } else {
      #pragma unroll
      for (int i = 0; i < 8; i++)
        #pragma unroll
        for (int r = 0; r < 4; r++) {
          const int row = i * 16 + fq * 4 + r;
          const float y = fmaxf((acc[i][r] - stats[row][0]) * stats[row][1] * vw + vl, 0.f);
          out[(size_t)(m0 + row) * 256 + col] = y;
        }
    }
  }
}

// ---------------------------------------------------------------------------
extern "C" void kernel_launch(void* const* d_in, const int* in_sizes, int n_in,
                              void* d_out, int out_size, void* d_ws, size_t ws_size,
                              hipStream_t stream)
{
  (void)in_sizes; (void)n_in; (void)out_size; (void)ws_size;
  const float* x     = (const float*)d_in[0];
  const float* fc0_w = (const float*)d_in[2];
  const float* fc0_b = (const float*)d_in[3];
  const float* ln0_w = (const float*)d_in[4];
  const float* ln0_b = (const float*)d_in[5];
  const float* ln1_w = (const float*)d_in[6];
  const float* ln1_b = (const float*)d_in[7];
  const float* ln2_w = (const float*)d_in[8];
  const float* ln2_b = (const float*)d_in[9];
  const float* wv0_w = (const float*)d_in[14];
  const float* wv0_b = (const float*)d_in[15];
  const float* wv1_w = (const float*)d_in[20];
  const float* wv1_b = (const float*)d_in[21];

  // workspace (~274 KB)
  char* ws = (char*)d_ws;
  u16*   w2_0 = (u16*)(ws);                  // 128 KB (K-major)
  u16*   w2_1 = (u16*)(ws + 131072ull);      // 128 KB
  u16*   w0T  = (u16*)(ws + 262144ull);      // 8 KB
  float* bvm0 = (float*)(ws + 270336ull);
  float* bvm1 = (float*)(ws + 271360ull);

  k_prep<<<33, 256, 0, stream>>>(fc0_w, wv0_w, wv0_b, wv1_w, wv1_b,
                                 w0T, w2_0, bvm0, w2_1, bvm1);
  k_mega<<<256, 1024, 0, stream>>>(x, w0T, fc0_b, ln0_w, ln0_b,
                                   w2_0, bvm0, ln1_w, ln1_b,
                                   w2_1, bvm1, ln2_w, ln2_b,
                                   (float*)d_out);
}

// Round 9
// 43.081 us; speedup vs baseline: 22.9344x; 2.2257x over previous
//
#include <hip/hip_runtime.h>
#include <stdint.h>

// TransConv fused form, round 9. Fixed geometry: B=16, L=2048, N=32768,
// Cin=16, D=256, H=4. Validated algebra (r2-r8, absmax 0.0625):
//   h <- relu(LN((h @ Wv_mean + bvm + h)/2)),  Wv_mean = head-mean of Wv,
// fc0: h0 = relu(LN(x @ fc0_w + fc0_b)).
//
// r7 probe: same-address L2 weight re-streaming caps ~9.4 TB/s chip-wide ->
// r9 stops re-reading weights from L2: each block stages weight K-chunks into
// LDS once (double-buffered, reg-staged async) and serves all 16 waves from
// LDS. Global weight traffic 268MB -> 67MB. I/O pattern reverted to r6's
// (clean FETCH/WRITE; r8's col-striped pattern doubled HBM traffic).

typedef unsigned short u16;
typedef unsigned int u32;
typedef __attribute__((ext_vector_type(8))) short bf16x8;
typedef __attribute__((ext_vector_type(8))) unsigned short u16x8;
typedef __attribute__((ext_vector_type(4))) float f32x4;

#define APAD 264   // As row stride (u16)

static __device__ __forceinline__ float bf2f(u16 u) {
  union { u32 i; float f; } c; c.i = ((u32)u) << 16; return c.f;
}
static __device__ __forceinline__ u16 f2bf(float f) {
  union { float ff; u32 i; } c; c.ff = f;
  u32 x = c.i;
  x += 0x7fffu + ((x >> 16) & 1u);   // RNE
  return (u16)(x >> 16);
}
static __device__ __forceinline__ bf16x8 as_bf(u16x8 v) {
  union { u16x8 a; bf16x8 b; } c; c.a = v; return c.b;
}

// ---------------------------------------------------------------------------
// Prep (unchanged from r5/r6). grid 33 x 256.
//  bid 0..31 : W2{L}[kt][d][q][e] = bf16(mean_h wv{L}[kt*32+q*8+e][h*256+d])
//  bid 32    : w0T[d][k] = bf16(fc0_w[k][d]);  bvm{L}[d] = mean_h bv{L}
// ---------------------------------------------------------------------------
__global__ __launch_bounds__(256) void k_prep(
    const float* __restrict__ fc0_w,
    const float* __restrict__ wv0, const float* __restrict__ bv0,
    const float* __restrict__ wv1, const float* __restrict__ bv1,
    u16* __restrict__ w0T,
    u16* __restrict__ w2_0, float* __restrict__ bvm0,
    u16* __restrict__ w2_1, float* __restrict__ bvm1)
{
  const int bid = blockIdx.x, tid = threadIdx.x;
  if (bid < 32) {
    __shared__ u16 t[64][72];
    const int L  = bid >> 4;
    const int ti = (bid >> 2) & 3;
    const int tj = bid & 3;
    const float* wv = L ? wv1 : wv0;
    u16* W2 = L ? w2_1 : w2_0;
    const int cl = tid >> 2, dq = tid & 3;
    #pragma unroll
    for (int e = 0; e < 16; e++) {
      const int dl = dq * 16 + e;
      const float* p = wv + (size_t)(ti * 64 + cl) * 1024 + tj * 64 + dl;
      t[cl][dl] = f2bf(0.25f * (p[0] + p[256] + p[512] + p[768]));
    }
    __syncthreads();
    const int dl = tid >> 2, cq = tid & 3;
    u16x8 v0, v1;
    #pragma unroll
    for (int e = 0; e < 8; e++) { v0[e] = t[cq * 16 + e][dl]; v1[e] = t[cq * 16 + 8 + e][dl]; }
    const int kt = ti * 2 + (cq >> 1);
    const int q0 = (cq & 1) * 2;
    const int d  = tj * 64 + dl;
    u16* dst = W2 + kt * 8192 + d * 32 + q0 * 8;
    *(u16x8*)dst = v0;
    *(u16x8*)(dst + 8) = v1;
  } else {
    const int d = tid;
    u16x8 r0, r1;
    #pragma unroll
    for (int k = 0; k < 8; k++) {
      r0[k] = f2bf(fc0_w[k * 256 + d]);
      r1[k] = f2bf(fc0_w[(k + 8) * 256 + d]);
    }
    *(u16x8*)(w0T + d * 16) = r0;
    *(u16x8*)(w0T + d * 16 + 8) = r1;
    float t0 = 0.f, t1 = 0.f;
    #pragma unroll
    for (int h = 0; h < 4; h++) { t0 += bv0[h * 256 + d]; t1 += bv1[h * 256 + d]; }
    bvm0[d] = 0.25f * t0;
    bvm1[d] = 0.25f * t1;
  }
}

// ---------------------------------------------------------------------------
// Mega kernel: 256 blocks x 1024 threads (16 waves), block owns 128 rows.
// Wave w: row-group wr = w>>2 (32 rows at wr*32), col-stripe wc = w&3
// (64 cols at wc*64). acc[2][4] of 16x16 frags per wave.
// C/D map (HW-verified m89/m91): row(in wave) = i*16 + fq*4 + r,
//                                col = wc*64 + j*16 + fr.
// Weights LDS-staged: 4 chunks of K=64 (32KB), double-buffered, 1 barrier/chunk.
// ---------------------------------------------------------------------------
__global__ __launch_bounds__(1024, 1) void k_mega(
    const float* __restrict__ x,
    const u16* __restrict__ w0T, const float* __restrict__ fc0_b,
    const float* __restrict__ ln0w, const float* __restrict__ ln0b,
    const u16* __restrict__ w2_0, const float* __restrict__ bvm0,
    const float* __restrict__ ln1w, const float* __restrict__ ln1b,
    const u16* __restrict__ w2_1, const float* __restrict__ bvm1,
    const float* __restrict__ ln2w, const float* __restrict__ ln2b,
    float* __restrict__ out)
{
  __shared__ u16 As[128 * APAD];             // 67.6 KB: the h tile (128 rows)
  __shared__ u16 Bs[2][16384];               // 64 KB: weight chunk double-buffer
  __shared__ float psum[4][128], pssq[4][128];
  __shared__ float stats[128][2];

  const int tid  = threadIdx.x;
  const int lane = tid & 63;
  const int w    = tid >> 6;
  const int wr   = w >> 2;          // row-group (0..3), 32 rows each
  const int wc   = w & 3;           // col-stripe (0..3), 64 cols each
  const int fr   = lane & 15;
  const int fq   = lane >> 4;
  const int kc   = fq << 3;         // k sub-chunk elem offset (0,8,16,24)
  const int m0   = blockIdx.x * 128;
  const int rbase = wr * 32;

  f32x4 acc[2][4];
  #pragma unroll
  for (int i = 0; i < 2; i++)
    #pragma unroll
    for (int j = 0; j < 4; j++)
      acc[i][j] = f32x4{0.f, 0.f, 0.f, 0.f};

  // ---- Phase 0 MFMA: fc0, K=16 zero-padded to 32, operands direct from global
  {
    bf16x8 af[2], bg[4];
    if (kc < 16) {
      #pragma unroll
      for (int i = 0; i < 2; i++) {
        const float* xp = x + (size_t)(m0 + rbase + i * 16 + fr) * 16 + kc;
        const f32x4 lo = *(const f32x4*)xp;
        const f32x4 hi = *(const f32x4*)(xp + 4);
        u16x8 v;
        #pragma unroll
        for (int e = 0; e < 4; e++) { v[e] = f2bf(lo[e]); v[4 + e] = f2bf(hi[e]); }
        af[i] = as_bf(v);
      }
      #pragma unroll
      for (int j = 0; j < 4; j++)
        bg[j] = as_bf(*(const u16x8*)(w0T + (wc * 64 + j * 16 + fr) * 16 + kc));
    } else {
      const u16x8 z = {0,0,0,0,0,0,0,0};
      #pragma unroll
      for (int i = 0; i < 2; i++) af[i] = as_bf(z);
      #pragma unroll
      for (int j = 0; j < 4; j++) bg[j] = as_bf(z);
    }
    #pragma unroll
    for (int i = 0; i < 2; i++)
      #pragma unroll
      for (int j = 0; j < 4; j++)
        acc[i][j] = __builtin_amdgcn_mfma_f32_16x16x32_bf16(af[i], bg[j], acc[i][j], 0, 0, 0);
  }

  // Phase 0 epilogue: +fc0_b, LN(ln0), relu -> As
  {
    float vb[4], vw[4], vl[4];
    #pragma unroll
    for (int j = 0; j < 4; j++) {
      const int c = wc * 64 + j * 16 + fr;
      vb[j] = fc0_b[c]; vw[j] = ln0w[c]; vl[j] = ln0b[c];
    }
    #pragma unroll
    for (int i = 0; i < 2; i++)
      #pragma unroll
      for (int r = 0; r < 4; r++) {
        const int row = rbase + i * 16 + fq * 4 + r;
        float s = 0.f, ss = 0.f;
        #pragma unroll
        for (int j = 0; j < 4; j++) {
          const float xv = acc[i][j][r] + vb[j];
          acc[i][j][r] = xv;
          s += xv; ss += xv * xv;
        }
        #pragma unroll
        for (int off = 1; off < 16; off <<= 1) {
          s  += __shfl_xor(s, off, 64);
          ss += __shfl_xor(ss, off, 64);
        }
        if (fr == 0) { psum[wc][row] = s; pssq[wc][row] = ss; }
      }
    __syncthreads();
    if (tid < 128) {
      const float s  = psum[0][tid] + psum[1][tid] + psum[2][tid] + psum[3][tid];
      const float ss = pssq[0][tid] + pssq[1][tid] + pssq[2][tid] + pssq[3][tid];
      const float mean = s * (1.0f / 256.0f);
      const float var  = ss * (1.0f / 256.0f) - mean * mean;
      stats[tid][0] = mean;
      stats[tid][1] = rsqrtf(var + 1e-5f);
    }
    __syncthreads();
    #pragma unroll
    for (int i = 0; i < 2; i++)
      #pragma unroll
      for (int r = 0; r < 4; r++) {
        const int row = rbase + i * 16 + fq * 4 + r;
        const float mean = stats[row][0], rstd = stats[row][1];
        #pragma unroll
        for (int j = 0; j < 4; j++) {
          const int col = wc * 64 + j * 16 + fr;
          const float y = fmaxf((acc[i][j][r] - mean) * rstd * vw[j] + vl[j], 0.f);
          const u32 self = f2bf(y);
          const u32 peer = __shfl_xor((int)self, 1, 64);   // pack bf16 pair
          if ((fr & 1) == 0)
            *(u32*)&As[row * APAD + col] = self | (peer << 16);
        }
      }
    __syncthreads();
  }

  // ---- Phases 1 & 2: h <- relu(LN((h @ W + bvm + h)/2)) ----
  #pragma unroll 1
  for (int p = 0; p < 2; p++) {
    const u16* W2 = p ? w2_1 : w2_0;
    const float* bvp = p ? bvm1 : bvm0;
    const float* lw  = p ? ln2w : ln1w;
    const float* lb  = p ? ln2b : ln1b;

    #pragma unroll
    for (int i = 0; i < 2; i++)
      #pragma unroll
      for (int j = 0; j < 4; j++)
        acc[i][j] = f32x4{0.f, 0.f, 0.f, 0.f};

    // ---- LDS-staged K-loop: 4 chunks of K=64 (16384 u16 each), dbuf ----
    // staging: thread tid copies elems [tid*8, tid*8+8) and [8192+tid*8, +8)
    u16x8 s0 = *(const u16x8*)(W2 + tid * 8);
    u16x8 s1 = *(const u16x8*)(W2 + 8192 + tid * 8);
    *(u16x8*)(&Bs[0][tid * 8]) = s0;
    *(u16x8*)(&Bs[0][8192 + tid * 8]) = s1;

    #pragma unroll
    for (int c = 0; c < 4; c++) {
      if (c < 3) {                       // issue next chunk's global loads
        s0 = *(const u16x8*)(W2 + (c + 1) * 16384 + tid * 8);
        s1 = *(const u16x8*)(W2 + (c + 1) * 16384 + 8192 + tid * 8);
      }
      __syncthreads();                   // buf[c&1] writes visible to all
      const u16* bbase = &Bs[c & 1][0];
      #pragma unroll
      for (int t = 0; t < 2; t++) {
        const int kt = c * 2 + t;
        bf16x8 a[2], b[4];
        #pragma unroll
        for (int i = 0; i < 2; i++)
          a[i] = *(const bf16x8*)(As + (rbase + i * 16 + fr) * APAD + kt * 32 + kc);
        #pragma unroll
        for (int j = 0; j < 4; j++)
          b[j] = *(const bf16x8*)(bbase + t * 8192 + (wc * 64 + j * 16 + fr) * 32 + kc);
        #pragma unroll
        for (int i = 0; i < 2; i++)
          #pragma unroll
          for (int j = 0; j < 4; j++)
            acc[i][j] = __builtin_amdgcn_mfma_f32_16x16x32_bf16(a[i], b[j], acc[i][j], 0, 0, 0);
      }
      if (c < 3) {                       // write next chunk into other buffer
        *(u16x8*)(&Bs[(c + 1) & 1][tid * 8]) = s0;
        *(u16x8*)(&Bs[(c + 1) & 1][8192 + tid * 8]) = s1;
      }
    }

    // epilogue: xv = (C + bvm + h_prev)/2, row-LN, relu
    float vb[4], vw[4], vl[4];
    #pragma unroll
    for (int j = 0; j < 4; j++) {
      const int c = wc * 64 + j * 16 + fr;
      vb[j] = bvp[c]; vw[j] = lw[c]; vl[j] = lb[c];
    }
    #pragma unroll
    for (int i = 0; i < 2; i++)
      #pragma unroll
      for (int r = 0; r < 4; r++) {
        const int row = rbase + i * 16 + fq * 4 + r;
        float s = 0.f, ss = 0.f;
        #pragma unroll
        for (int j = 0; j < 4; j++) {
          const int col = wc * 64 + j * 16 + fr;
          const float prev = bf2f(As[row * APAD + col]);
          const float xv = (acc[i][j][r] + vb[j] + prev) * 0.5f;
          acc[i][j][r] = xv;
          s += xv; ss += xv * xv;
        }
        #pragma unroll
        for (int off = 1; off < 16; off <<= 1) {
          s  += __shfl_xor(s, off, 64);
          ss += __shfl_xor(ss, off, 64);
        }
        if (fr == 0) { psum[wc][row] = s; pssq[wc][row] = ss; }
      }
    __syncthreads();
    if (tid < 128) {
      const float s  = psum[0][tid] + psum[1][tid] + psum[2][tid] + psum[3][tid];
      const float ss = pssq[0][tid] + pssq[1][tid] + pssq[2][tid] + pssq[3][tid];
      const float mean = s * (1.0f / 256.0f);
      const float var  = ss * (1.0f / 256.0f) - mean * mean;
      stats[tid][0] = mean;
      stats[tid][1] = rsqrtf(var + 1e-5f);
    }
    __syncthreads();
    if (p == 0) {
      #pragma unroll
      for (int i = 0; i < 2; i++)
        #pragma unroll
        for (int r = 0; r < 4; r++) {
          const int row = rbase + i * 16 + fq * 4 + r;
          const float mean = stats[row][0], rstd = stats[row][1];
          #pragma unroll
          for (int j = 0; j < 4; j++) {
            const int col = wc * 64 + j * 16 + fr;
            const float y = fmaxf((acc[i][j][r] - mean) * rstd * vw[j] + vl[j], 0.f);
            const u32 self = f2bf(y);
            const u32 peer = __shfl_xor((int)self, 1, 64);
            if ((fr & 1) == 0)
              *(u32*)&As[row * APAD + col] = self | (peer << 16);
          }
        }
      __syncthreads();
    } else {
      #pragma unroll
      for (int i = 0; i < 2; i++)
        #pragma unroll
        for (int r = 0; r < 4; r++) {
          const int row = rbase + i * 16 + fq * 4 + r;
          const float mean = stats[row][0], rstd = stats[row][1];
          #pragma unroll
          for (int j = 0; j < 4; j++) {
            const int col = wc * 64 + j * 16 + fr;
            const float y = fmaxf((acc[i][j][r] - mean) * rstd * vw[j] + vl[j], 0.f);
            out[(size_t)(m0 + row) * 256 + col] = y;
          }
        }
    }
  }
}

// ---------------------------------------------------------------------------
extern "C" void kernel_launch(void* const* d_in, const int* in_sizes, int n_in,
                              void* d_out, int out_size, void* d_ws, size_t ws_size,
                              hipStream_t stream)
{
  (void)in_sizes; (void)n_in; (void)out_size; (void)ws_size;
  const float* x     = (const float*)d_in[0];
  const float* fc0_w = (const float*)d_in[2];
  const float* fc0_b = (const float*)d_in[3];
  const float* ln0_w = (const float*)d_in[4];
  const float* ln0_b = (const float*)d_in[5];
  const float* ln1_w = (const float*)d_in[6];
  const float* ln1_b = (const float*)d_in[7];
  const float* ln2_w = (const float*)d_in[8];
  const float* ln2_b = (const float*)d_in[9];
  const float* wv0_w = (const float*)d_in[14];
  const float* wv0_b = (const float*)d_in[15];
  const float* wv1_w = (const float*)d_in[20];
  const float* wv1_b = (const float*)d_in[21];

  // workspace (~274 KB)
  char* ws = (char*)d_ws;
  u16*   w2_0 = (u16*)(ws);                  // 128 KB (K-major)
  u16*   w2_1 = (u16*)(ws + 131072ull);      // 128 KB
  u16*   w0T  = (u16*)(ws + 262144ull);      // 8 KB
  float* bvm0 = (float*)(ws + 270336ull);
  float* bvm1 = (float*)(ws + 271360ull);

  k_prep<<<33, 256, 0, stream>>>(fc0_w, wv0_w, wv0_b, wv1_w, wv1_b,
                                 w0T, w2_0, bvm0, w2_1, bvm1);
  k_mega<<<256, 1024, 0, stream>>>(x, w0T, fc0_b, ln0_w, ln0_b,
                                   w2_0, bvm0, ln1_w, ln1_b,
                                   w2_1, bvm1, ln2_w, ln2_b,
                                   (float*)d_out);
}